// Round 1
// baseline (10586.913 us; speedup 1.0000x reference)
//
#include <hip/hip_runtime.h>

#define Bv    64
#define Sv    200
#define DKv   32
#define NQ1v  4097
#define NWG   4      // workgroups per batch element
#define TPB   512    // threads per workgroup
#define ROWS  2      // h-rows per thread (4*512*2 = 4096, +1 special)
#define NSTEP 199

__device__ __forceinline__ float fsig(float x) {
  return __builtin_amdgcn_rcpf(1.0f + __builtin_amdgcn_exp2f(x * -1.4426950408889634f));
}
__device__ __forceinline__ float ftanh_(float x) {
  return fmaf(2.0f, fsig(2.0f * x), -1.0f);
}

__global__ void lpkt_init(unsigned int* cnt, float* out) {
  int i = threadIdx.x;
  if (i < Bv) { cnt[i * 16] = 0u; out[i * Sv] = 0.0f; }
}

__global__ __launch_bounds__(TPB, 2) void lpkt_main(
    const int* __restrict__ e_data, const int* __restrict__ at_data,
    const int* __restrict__ it_data, const float* __restrict__ a_data,
    const float* __restrict__ q_matrix,
    const float* __restrict__ E_e, const float* __restrict__ E_at, const float* __restrict__ E_it,
    const float* __restrict__ W1, const float* __restrict__ b1,
    const float* __restrict__ W2, const float* __restrict__ b2,
    const float* __restrict__ W3, const float* __restrict__ b3,
    const float* __restrict__ W4, const float* __restrict__ b4,
    const float* __restrict__ W5, const float* __restrict__ b5,
    const float* __restrict__ h0, float* __restrict__ out,
    float* __restrict__ partial, unsigned int* __restrict__ cnt)
{
  const int tid  = threadIdx.x;
  const int wg   = blockIdx.x & (NWG - 1);
  const int b    = blockIdx.x / NWG;
  const int k    = tid & 31;
  const int p    = tid >> 5;    // 0..15
  const int wave = tid >> 6;    // 0..7

  __shared__ float ht_lds[DKv], lp_lds[DKv], lc_lds[DKv], it_lds[DKv], en_lds[DKv];
  __shared__ float xw_lds[96], x_lds[128];
  __shared__ float LG_lds[DKv], c_lds[DKv];
  __shared__ float red[16][DKv], red2[16][DKv];
  __shared__ float wred[8][DKv];
  __shared__ float h49[DKv], spec_lds[DKv];

  const int nbase = wg * (TPB * ROWS);

  // ---- persistent register state: rows nbase + r*TPB + tid
  float h[ROWS][DKv];
#pragma unroll
  for (int r = 0; r < ROWS; r++) {
    const float4* hp = (const float4*)(h0 + (size_t)(nbase + r * TPB + tid) * DKv);
#pragma unroll
    for (int i = 0; i < 8; i++) {
      float4 v = hp[i];
      h[r][i * 4 + 0] = v.x; h[r][i * 4 + 1] = v.y;
      h[r][i * 4 + 2] = v.z; h[r][i * 4 + 3] = v.w;
    }
  }
  if (wg == 0 && tid < DKv) h49[tid] = h0[4096 * DKv + tid];

  const int e0 = e_data[b * Sv];
  const float* q0 = q_matrix + (size_t)e0 * NQ1v;
  float qc[ROWS];
#pragma unroll
  for (int r = 0; r < ROWS; r++) qc[r] = q0[nbase + r * TPB + tid];
  float qc49 = (wg == 0) ? q0[4096] : 0.0f;
  __syncthreads();

  // =================== phase 0: h_tilde0 ===================
  float htacc[DKv];
#pragma unroll
  for (int kk = 0; kk < DKv; kk++) htacc[kk] = 0.0f;
#pragma unroll
  for (int r = 0; r < ROWS; r++) {
#pragma unroll
    for (int kk = 0; kk < DKv; kk++) htacc[kk] = fmaf(qc[r], h[r][kk], htacc[kk]);
  }
  if (wg == 0 && tid < DKv) spec_lds[tid] = qc49 * h49[tid];

#pragma unroll
  for (int kk = 0; kk < DKv; kk++) {
    float v = htacc[kk];
#pragma unroll
    for (int m = 1; m < 64; m <<= 1) v += __shfl_xor(v, m);
    htacc[kk] = v;
  }
  if ((tid & 63) == 0) {
#pragma unroll
    for (int kk = 0; kk < DKv; kk += 4) {
      float4 v4 = make_float4(htacc[kk], htacc[kk + 1], htacc[kk + 2], htacc[kk + 3]);
      *(float4*)&wred[wave][kk] = v4;
    }
  }
  __syncthreads();
  {
    const int pbuf = 0;
    if (tid < DKv) {
      float s = (wg == 0) ? spec_lds[tid] : 0.0f;
#pragma unroll
      for (int wv = 0; wv < 8; wv++) s += wred[wv][tid];
      __hip_atomic_store(&partial[(((size_t)b * 2 + pbuf) * NWG + wg) * DKv + tid], s,
                         __ATOMIC_RELAXED, __HIP_MEMORY_SCOPE_AGENT);
    }
    __threadfence();
    __syncthreads();
    if (tid == 0) {
      __hip_atomic_fetch_add(&cnt[b * 16], 1u, __ATOMIC_RELEASE, __HIP_MEMORY_SCOPE_AGENT);
      unsigned target = NWG;
      while (__hip_atomic_load(&cnt[b * 16], __ATOMIC_ACQUIRE, __HIP_MEMORY_SCOPE_AGENT) < target)
        __builtin_amdgcn_s_sleep(1);
    }
    __syncthreads();
    if (tid < DKv) {
      float s = 0.0f;
#pragma unroll
      for (int w2 = 0; w2 < NWG; w2++)
        s += __hip_atomic_load(&partial[(((size_t)b * 2 + pbuf) * NWG + w2) * DKv + tid],
                               __ATOMIC_RELAXED, __HIP_MEMORY_SCOPE_AGENT);
      ht_lds[tid] = s;
    }
    if (tid < DKv) lp_lds[tid] = 0.0f;
    __syncthreads();
  }

  // =================== time loop ===================
  for (int t = 0; t < NSTEP; t++) {
    const int ecur  = e_data[b * Sv + t];
    const int enext = e_data[b * Sv + t + 1];
    const int atc   = at_data[b * Sv + t];
    const int itc   = it_data[b * Sv + t];
    const float av  = a_data[b * Sv + t];

    // ---- stage embeddings
    if (tid < 96)
      xw_lds[tid] = (tid < 32) ? E_e[(size_t)ecur * DKv + tid]
                  : (tid < 64) ? E_at[(size_t)atc * DKv + (tid - 32)] : av;
    if (tid < DKv) {
      it_lds[tid] = E_it[(size_t)itc * DKv + tid];
      en_lds[tid] = E_e[(size_t)enext * DKv + tid];
    }
    __syncthreads();

    // ---- learning_cur = xw @ W1[k,:96] + b1   (split-96 over p<12)
    {
      float lpart = 0.0f;
      if (p < 12) {
#pragma unroll
        for (int j = 0; j < 8; j += 4) {
          float4 w = *(const float4*)&W1[k * 96 + p * 8 + j];
          lpart = fmaf(xw_lds[p * 8 + j + 0], w.x, lpart);
          lpart = fmaf(xw_lds[p * 8 + j + 1], w.y, lpart);
          lpart = fmaf(xw_lds[p * 8 + j + 2], w.z, lpart);
          lpart = fmaf(xw_lds[p * 8 + j + 3], w.w, lpart);
        }
      }
      red[p][k] = lpart;
    }
    __syncthreads();
    if (tid < DKv) {
      float s = b1[tid];
#pragma unroll
      for (int pp = 0; pp < 12; pp++) s += red[pp][tid];
      lc_lds[tid] = s;
    }
    __syncthreads();
    if (tid < 128)
      x_lds[tid] = (tid < 32) ? lp_lds[tid] : (tid < 64) ? it_lds[tid - 32]
                 : (tid < 96) ? lc_lds[tid - 64] : ht_lds[tid - 96];
    __syncthreads();

    // ---- lg/gl: x(128) @ W2.T, W3.T  (split-128 over 16 parts)
    {
      float p2 = 0.0f, p3 = 0.0f;
#pragma unroll
      for (int j = 0; j < 8; j += 4) {
        float4 w2v = *(const float4*)&W2[k * 128 + p * 8 + j];
        float4 w3v = *(const float4*)&W3[k * 128 + p * 8 + j];
        float x0 = x_lds[p * 8 + j + 0], x1 = x_lds[p * 8 + j + 1];
        float x2 = x_lds[p * 8 + j + 2], x3 = x_lds[p * 8 + j + 3];
        p2 = fmaf(x0, w2v.x, p2); p2 = fmaf(x1, w2v.y, p2);
        p2 = fmaf(x2, w2v.z, p2); p2 = fmaf(x3, w2v.w, p2);
        p3 = fmaf(x0, w3v.x, p3); p3 = fmaf(x1, w3v.y, p3);
        p3 = fmaf(x2, w3v.z, p3); p3 = fmaf(x3, w3v.w, p3);
      }
      red[p][k] = p2; red2[p][k] = p3;
    }
    __syncthreads();
    if (tid < DKv) {
      float s2 = b2[tid], s3 = b3[tid];
#pragma unroll
      for (int pp = 0; pp < 16; pp++) { s2 += red[pp][tid]; s3 += red2[pp][tid]; }
      float lg = ftanh_(s2);
      float gl = fsig(s3);
      LG_lds[tid] = gl * (lg + 1.0f) * 0.5f;
    }
    __syncthreads();

    // ---- c = LG @ W4l.T + it @ W4i.T + b4   (64 terms over 16 parts)
    {
      float4 w = *(const float4*)&W4[k * 96 + 32 + p * 4];
      float u0, u1, u2, u3;
      if (p < 8) { u0 = LG_lds[p*4+0]; u1 = LG_lds[p*4+1]; u2 = LG_lds[p*4+2]; u3 = LG_lds[p*4+3]; }
      else       { u0 = it_lds[p*4-32]; u1 = it_lds[p*4-31]; u2 = it_lds[p*4-30]; u3 = it_lds[p*4-29]; }
      float pc = 0.0f;
      pc = fmaf(u0, w.x, pc); pc = fmaf(u1, w.y, pc);
      pc = fmaf(u2, w.z, pc); pc = fmaf(u3, w.w, pc);
      red[p][k] = pc;
    }
    __syncthreads();
    if (tid < DKv) {
      float s = b4[tid];
#pragma unroll
      for (int pp = 0; pp < 16; pp++) s += red[pp][tid];
      c_lds[tid] = s;
    }
    __syncthreads();

    // ---- q_next row
    const float* qnr = q_matrix + (size_t)enext * NQ1v;
    float qn[ROWS];
#pragma unroll
    for (int r = 0; r < ROWS; r++) qn[r] = qnr[nbase + r * TPB + tid];
    float qn49 = (wg == 0) ? qnr[4096] : 0.0f;

    // ---- main row update: gamma = sigmoid(W4h @ h + c); h = qc*LG + gamma*h
#pragma unroll
    for (int kk = 0; kk < DKv; kk++) htacc[kk] = 0.0f;
    {
      float g0[DKv], g1[DKv];
#pragma unroll
      for (int kk = 0; kk < DKv; kk++) {
        float a0 = c_lds[kk], a1 = a0;
#pragma unroll
        for (int d = 0; d < DKv; d += 4) {
          float4 w = *(const float4*)&W4[kk * 96 + d];   // uniform addr -> s_load
          a0 = fmaf(w.x, h[0][d + 0], a0); a1 = fmaf(w.x, h[1][d + 0], a1);
          a0 = fmaf(w.y, h[0][d + 1], a0); a1 = fmaf(w.y, h[1][d + 1], a1);
          a0 = fmaf(w.z, h[0][d + 2], a0); a1 = fmaf(w.z, h[1][d + 2], a1);
          a0 = fmaf(w.w, h[0][d + 3], a0); a1 = fmaf(w.w, h[1][d + 3], a1);
        }
        g0[kk] = fsig(a0); g1[kk] = fsig(a1);
      }
      float qc0 = qc[0], qc1 = qc[1], qn0 = qn[0], qn1 = qn[1];
#pragma unroll
      for (int kk = 0; kk < DKv; kk++) {
        float LGk = LG_lds[kk];
        float h0n = fmaf(g0[kk], h[0][kk], qc0 * LGk);
        float h1n = fmaf(g1[kk], h[1][kk], qc1 * LGk);
        h[0][kk] = h0n; h[1][kk] = h1n;
        htacc[kk] = fmaf(qn0, h0n, fmaf(qn1, h1n, htacc[kk]));
      }
    }

    // ---- special row n=4096 (wg0, wave0 lanes<32, LDS-resident)
    if (wg == 0 && tid < DKv) {
      float hh[DKv];
#pragma unroll
      for (int i = 0; i < DKv; i += 4) {
        float4 v = *(const float4*)&h49[i];
        hh[i] = v.x; hh[i + 1] = v.y; hh[i + 2] = v.z; hh[i + 3] = v.w;
      }
      float acc = c_lds[tid];
#pragma unroll
      for (int d = 0; d < DKv; d += 4) {
        float4 w = *(const float4*)&W4[tid * 96 + d];
        acc = fmaf(w.x, hh[d + 0], acc); acc = fmaf(w.y, hh[d + 1], acc);
        acc = fmaf(w.z, hh[d + 2], acc); acc = fmaf(w.w, hh[d + 3], acc);
      }
      float g = fsig(acc);
      float hold = h49[tid];
      float hn = fmaf(g, hold, qc49 * LG_lds[tid]);
      h49[tid] = hn;
      spec_lds[tid] = qn49 * hn;
    }

    // ---- reduce htacc: wave butterfly -> LDS -> WG partial
#pragma unroll
    for (int kk = 0; kk < DKv; kk++) {
      float v = htacc[kk];
#pragma unroll
      for (int m = 1; m < 64; m <<= 1) v += __shfl_xor(v, m);
      htacc[kk] = v;
    }
    if ((tid & 63) == 0) {
#pragma unroll
      for (int kk = 0; kk < DKv; kk += 4) {
        float4 v4 = make_float4(htacc[kk], htacc[kk + 1], htacc[kk + 2], htacc[kk + 3]);
        *(float4*)&wred[wave][kk] = v4;
      }
    }
    __syncthreads();

    // ---- cross-WG sync (per-b, agent-scope atomics, double-buffered)
    const int phase = t + 1;
    const int pbuf = phase & 1;
    if (tid < DKv) {
      float s = (wg == 0) ? spec_lds[tid] : 0.0f;
#pragma unroll
      for (int wv = 0; wv < 8; wv++) s += wred[wv][tid];
      __hip_atomic_store(&partial[(((size_t)b * 2 + pbuf) * NWG + wg) * DKv + tid], s,
                         __ATOMIC_RELAXED, __HIP_MEMORY_SCOPE_AGENT);
    }
    __threadfence();
    __syncthreads();
    if (tid == 0) {
      __hip_atomic_fetch_add(&cnt[b * 16], 1u, __ATOMIC_RELEASE, __HIP_MEMORY_SCOPE_AGENT);
      unsigned target = (unsigned)NWG * (phase + 1);
      while (__hip_atomic_load(&cnt[b * 16], __ATOMIC_ACQUIRE, __HIP_MEMORY_SCOPE_AGENT) < target)
        __builtin_amdgcn_s_sleep(1);
    }
    __syncthreads();
    if (tid < DKv) {
      float s = 0.0f;
#pragma unroll
      for (int w2 = 0; w2 < NWG; w2++)
        s += __hip_atomic_load(&partial[(((size_t)b * 2 + pbuf) * NWG + w2) * DKv + tid],
                               __ATOMIC_RELAXED, __HIP_MEMORY_SCOPE_AGENT);
      ht_lds[tid] = s;
    }
    __syncthreads();

    // ---- y output (wg0 only)
    if (wg == 0 && tid < 64) {
      const int pp = tid >> 5;
      float acc = 0.0f;
#pragma unroll
      for (int j = 0; j < 32; j += 4) {
        float4 w = *(const float4*)&W5[k * 64 + pp * 32 + j];
        float z0, z1, z2, z3;
        if (pp == 0) { z0 = en_lds[j]; z1 = en_lds[j+1]; z2 = en_lds[j+2]; z3 = en_lds[j+3]; }
        else         { z0 = ht_lds[j]; z1 = ht_lds[j+1]; z2 = ht_lds[j+2]; z3 = ht_lds[j+3]; }
        acc = fmaf(z0, w.x, acc); acc = fmaf(z1, w.y, acc);
        acc = fmaf(z2, w.z, acc); acc = fmaf(z3, w.w, acc);
      }
      red2[pp][k] = acc;
    }
    __syncthreads();
    if (wg == 0 && tid < DKv) {
      float s = fsig(b5[tid] + red2[0][tid] + red2[1][tid]);
#pragma unroll
      for (int m = 1; m < 32; m <<= 1) s += __shfl_xor(s, m);
      if (tid == 0) out[b * Sv + t + 1] = s * (1.0f / DKv);
    }

    // ---- carries
    if (tid < DKv) lp_lds[tid] = lc_lds[tid];
#pragma unroll
    for (int r = 0; r < ROWS; r++) qc[r] = qn[r];
    qc49 = qn49;
    __syncthreads();
  }
}

extern "C" void kernel_launch(void* const* d_in, const int* in_sizes, int n_in,
                              void* d_out, int out_size, void* d_ws, size_t ws_size,
                              hipStream_t stream) {
  const int*   e_data   = (const int*)d_in[0];
  const int*   at_data  = (const int*)d_in[1];
  const int*   it_data  = (const int*)d_in[2];
  const float* a_data   = (const float*)d_in[3];
  const float* q_matrix = (const float*)d_in[4];
  const float* E_e      = (const float*)d_in[5];
  const float* E_at     = (const float*)d_in[6];
  const float* E_it     = (const float*)d_in[7];
  const float* W1 = (const float*)d_in[8];
  const float* b1 = (const float*)d_in[9];
  const float* W2 = (const float*)d_in[10];
  const float* b2 = (const float*)d_in[11];
  const float* W3 = (const float*)d_in[12];
  const float* b3 = (const float*)d_in[13];
  const float* W4 = (const float*)d_in[14];
  const float* b4 = (const float*)d_in[15];
  const float* W5 = (const float*)d_in[16];
  const float* b5 = (const float*)d_in[17];
  const float* h0 = (const float*)d_in[18];
  float* out = (float*)d_out;

  float* partial = (float*)d_ws;
  unsigned int* cnt = (unsigned int*)((char*)d_ws + (size_t)Bv * 2 * NWG * DKv * sizeof(float));

  lpkt_init<<<1, 64, 0, stream>>>(cnt, out);
  lpkt_main<<<dim3(Bv * NWG), dim3(TPB), 0, stream>>>(
      e_data, at_data, it_data, a_data, q_matrix, E_e, E_at, E_it,
      W1, b1, W2, b2, W3, b3, W4, b4, W5, b5, h0, out, partial, cnt);
}